// Round 6
// baseline (365.398 us; speedup 1.0000x reference)
//
#include <hip/hip_runtime.h>
#include <stdint.h>

typedef __bf16 bf16x8 __attribute__((ext_vector_type(8)));
typedef float  floatx4 __attribute__((ext_vector_type(4)));

__device__ __forceinline__ unsigned short f2b(float x){
    unsigned u = __float_as_uint(x);
    u = u + 0x7FFFu + ((u >> 16) & 1u);          // RNE
    return (unsigned short)(u >> 16);
}
__device__ __forceinline__ float b2f(unsigned short h){
    return __uint_as_float(((unsigned)h) << 16);
}

// ================= CSR build: two-level counting sort (no global atomics) ====
// bin = dst >> 7 (128 nodes per bin). EPB = 8192 edges per hist/scatter block.

__global__ __launch_bounds__(256) void k_hist(const int* __restrict__ dst,
                                              int* __restrict__ hist,
                                              int E_, int nbins, int nblk){
    __shared__ int h[1024];
    int t = threadIdx.x, blk = blockIdx.x;
    for (int i = t; i < nbins; i += 256) h[i] = 0;
    __syncthreads();
    int base = blk * 8192;
    #pragma unroll
    for (int j = 0; j < 8; j++){
        int e = base + (j * 256 + t) * 4;
        if (e < E_){
            int4 d = *(const int4*)(dst + e);
            atomicAdd(&h[d.x >> 7], 1);
            atomicAdd(&h[d.y >> 7], 1);
            atomicAdd(&h[d.z >> 7], 1);
            atomicAdd(&h[d.w >> 7], 1);
        }
    }
    __syncthreads();
    for (int i = t; i < nbins; i += 256) hist[(size_t)i * nblk + blk] = h[i];
}

// per-bin exclusive scan across blocks, in place; bin totals out. 1 wave/bin.
__global__ __launch_bounds__(64) void k_binscanA(int* __restrict__ hist,
                                                 int* __restrict__ btot, int nblk){
    int bin = blockIdx.x, lane = threadIdx.x;
    int carry = 0;
    for (int base = 0; base < nblk; base += 64){
        int idx = bin * nblk + base + lane;
        bool inb = (base + lane) < nblk;
        int v = inb ? hist[idx] : 0;
        int orig = v;
        #pragma unroll
        for (int o = 1; o < 64; o <<= 1){
            int u = __shfl_up(v, o);
            if (lane >= o) v += u;
        }
        if (inb) hist[idx] = v - orig + carry;
        carry += __shfl(v, 63);
    }
    if (lane == 0) btot[bin] = carry;
}

// scan of bin totals -> binoff[0..nbins]  (requires nbins <= 1024)
__global__ __launch_bounds__(1024) void k_binscanB(const int* __restrict__ btot,
                                                   int* __restrict__ boff, int nbins){
    __shared__ int s[1024];
    int t = threadIdx.x;
    s[t] = (t < nbins) ? btot[t] : 0;
    __syncthreads();
    for (int o = 1; o < 1024; o <<= 1){
        int v = (t >= o) ? s[t - o] : 0;
        __syncthreads();
        s[t] += v;
        __syncthreads();
    }
    if (t == 0) boff[0] = 0;
    if (t < nbins) boff[t + 1] = s[t];
}

// partition edges into bin segments; positions via LDS counters only.
// packed word (UNSIGNED): (dst & 127) << 25 | src     (needs N < 2^25)
__global__ __launch_bounds__(256) void k_scatter(const int* __restrict__ src,
                                                 const int* __restrict__ dst,
                                                 const int* __restrict__ hist,
                                                 const int* __restrict__ boff,
                                                 unsigned* __restrict__ part,
                                                 int E_, int nbins, int nblk){
    __shared__ int cur[1024];
    int t = threadIdx.x, blk = blockIdx.x;
    for (int i = t; i < nbins; i += 256)
        cur[i] = boff[i] + hist[(size_t)i * nblk + blk];
    __syncthreads();
    int base = blk * 8192;
    #pragma unroll
    for (int j = 0; j < 8; j++){
        int e = base + (j * 256 + t) * 4;
        if (e < E_){
            int4 d = *(const int4*)(dst + e);
            int4 s = *(const int4*)(src + e);
            int p0 = atomicAdd(&cur[d.x >> 7], 1);
            part[p0] = ((unsigned)(d.x & 127) << 25) | (unsigned)s.x;
            int p1 = atomicAdd(&cur[d.y >> 7], 1);
            part[p1] = ((unsigned)(d.y & 127) << 25) | (unsigned)s.y;
            int p2 = atomicAdd(&cur[d.z >> 7], 1);
            part[p2] = ((unsigned)(d.z & 127) << 25) | (unsigned)s.z;
            int p3 = atomicAdd(&cur[d.w >> 7], 1);
            part[p3] = ((unsigned)(d.w & 127) << 25) | (unsigned)s.w;
        }
    }
}

// one block per bin: local count/scan/rank in LDS; coalesced csr write.
// Also emits cnt[node], off[node], dinv[node] for the bin's 128 nodes.
__global__ __launch_bounds__(256) void k_binsort(const unsigned* __restrict__ part,
                                                 const int* __restrict__ boff,
                                                 int* __restrict__ csr,
                                                 int* __restrict__ cnt,
                                                 int* __restrict__ off,
                                                 float* __restrict__ dinv,
                                                 int n, int nbins){
    int b = blockIdx.x, t = threadIdx.x;
    int s0 = boff[b], s1 = boff[b + 1], len = s1 - s0;
    __shared__ int cl[128], sc[128], cur[128];
    __shared__ unsigned buf[4096], outb[4096];
    if (t < 128){ cl[t] = 0; cur[t] = 0; }
    __syncthreads();
    if (len <= 4096){
        for (int i = t; i < len; i += 256) buf[i] = part[s0 + i];
        __syncthreads();
        for (int i = t; i < len; i += 256) atomicAdd(&cl[buf[i] >> 25], 1);
        __syncthreads();
        if (t < 128) sc[t] = cl[t];
        __syncthreads();
        for (int o = 1; o < 128; o <<= 1){
            int v = 0;
            if (t < 128 && t >= o) v = sc[t - o];
            __syncthreads();
            if (t < 128) sc[t] += v;
            __syncthreads();
        }
        for (int i = t; i < len; i += 256){
            unsigned w = buf[i];
            int nd = (int)(w >> 25);
            int p = (sc[nd] - cl[nd]) + atomicAdd(&cur[nd], 1);
            outb[p] = w & 0x1FFFFFFu;
        }
        __syncthreads();
        for (int i = t; i < len; i += 256) csr[s0 + i] = (int)outb[i];
    } else {
        // fallback (never expected at these sizes): two global passes
        for (int i = t; i < len; i += 256) atomicAdd(&cl[part[s0 + i] >> 25], 1);
        __syncthreads();
        if (t < 128) sc[t] = cl[t];
        __syncthreads();
        for (int o = 1; o < 128; o <<= 1){
            int v = 0;
            if (t < 128 && t >= o) v = sc[t - o];
            __syncthreads();
            if (t < 128) sc[t] += v;
            __syncthreads();
        }
        for (int i = t; i < len; i += 256){
            unsigned w = part[s0 + i];
            int nd = (int)(w >> 25);
            int p = (sc[nd] - cl[nd]) + atomicAdd(&cur[nd], 1);
            csr[s0 + p] = (int)(w & 0x1FFFFFFu);
        }
    }
    if (t < 128){
        int node = b * 128 + t;
        if (node < n){
            cnt[node] = cl[t];
            off[node] = s0 + (sc[t] - cl[t]);
            dinv[node] = rsqrtf((float)cl[t] + 1.0f);
        }
    }
}

// ---------------- weight reorder (W1 only) to MFMA B-fragment order ------------
__global__ __launch_bounds__(256) void k_wconv(const float* __restrict__ W1,
                                               unsigned short* __restrict__ wf1){
    int lf = blockIdx.x * 256 + threadIdx.x;
    if (lf >= 2048) return;
    int lane = lf & 63;
    int ctkc = lf >> 6;
    int kc = ctkc & 3, ct = ctkc >> 2;
    int col = ct * 16 + (lane & 15);
    int k0  = kc * 32 + (lane >> 4) * 8;
    unsigned short* d = wf1 + (size_t)lf * 8;
    #pragma unroll
    for (int j = 0; j < 8; j++) d[j] = f2b(W1[(k0 + j) * 128 + col]);
}

// ---------------- GEMM1: hs1 = bf16( (x @ W1) * dinv[row] ) ----------------
__global__ __launch_bounds__(256) void k_gemm1(const float* __restrict__ x,
                                               const unsigned short* __restrict__ wf,
                                               const float* __restrict__ dinv,
                                               unsigned short* __restrict__ hs, int n){
    __shared__ unsigned short Wl[16384];
    __shared__ unsigned short Al[64 * 136];
    int t = threadIdx.x;
    long rowBase = (long)blockIdx.x * 64;
    {
        const uint4* s4 = (const uint4*)wf;
        uint4* d4 = (uint4*)Wl;
        #pragma unroll
        for (int i = 0; i < 8; i++) d4[t + i * 256] = s4[t + i * 256];
    }
    {
        const float4* xs = (const float4*)(x + rowBase * 128);
        #pragma unroll
        for (int k = 0; k < 8; k++){
            int i = t + k * 256;
            int r = i >> 5, c4 = (i & 31) << 2;
            float4 v = make_float4(0.f, 0.f, 0.f, 0.f);
            if (rowBase + r < n) v = xs[i];
            unsigned lo = (unsigned)f2b(v.x) | ((unsigned)f2b(v.y) << 16);
            unsigned hi = (unsigned)f2b(v.z) | ((unsigned)f2b(v.w) << 16);
            *(uint2*)&Al[r * 136 + c4] = make_uint2(lo, hi);
        }
    }
    __syncthreads();
    int w = t >> 6, lane = t & 63, lr = lane & 15, q = lane >> 4;
    floatx4 zero = {0.f, 0.f, 0.f, 0.f};
    floatx4 acc[8];
    #pragma unroll
    for (int ct = 0; ct < 8; ct++) acc[ct] = zero;
    #pragma unroll
    for (int kc = 0; kc < 4; kc++){
        bf16x8 af = *(const bf16x8*)&Al[(w * 16 + lr) * 136 + kc * 32 + q * 8];
        #pragma unroll
        for (int ct = 0; ct < 8; ct++){
            bf16x8 bf = *(const bf16x8*)&Wl[((ct * 4 + kc) * 64 + lane) * 8];
            acc[ct] = __builtin_amdgcn_mfma_f32_16x16x32_bf16(af, bf, acc[ct], 0, 0, 0);
        }
    }
    long r0 = rowBase + w * 16 + q * 4;
    #pragma unroll
    for (int r = 0; r < 4; r++){
        long row = r0 + r;
        if (row >= n) continue;
        float dv = dinv[row];
        unsigned short* orow = hs + row * 128 + lr;
        #pragma unroll
        for (int ct = 0; ct < 8; ct++) orow[ct * 16] = f2b(acc[ct][r] * dv);
    }
}

// ---- fused agg1 + gemm2: hs2[i] = bf16( (relu(dinv_i*(sum hs1[src]+hs1[i])+b1) @ W2) * dinv_i )
// wave per node (grid-stride), unrolled-x8 gather; per-node 128->64 projection
// via LDS broadcast of the z1 row against W2 staged fp32 in LDS.
__global__ __launch_bounds__(256) void k_agg1g2(const unsigned short* __restrict__ hs,
                                                const int* __restrict__ off,
                                                const int* __restrict__ cnt,
                                                const int* __restrict__ csr,
                                                const float* __restrict__ dinv,
                                                const float* __restrict__ b1,
                                                const float* __restrict__ W2,
                                                unsigned short* __restrict__ hs2,
                                                int n, int nwaves){
    __shared__ float W2l[128 * 64];    // 32 KB
    __shared__ float zrow[4][128];     // 2 KB, one row per wave
    int t = threadIdx.x;
    {
        const float4* w4 = (const float4*)W2;
        float4* d4 = (float4*)W2l;
        #pragma unroll
        for (int i = 0; i < 8; i++) d4[t + i * 256] = w4[t + i * 256];
    }
    __syncthreads();
    int wband = t >> 6, lane = t & 63;
    float2 bb = ((const float2*)b1)[lane];
    for (int wid = blockIdx.x * 4 + wband; wid < n; wid += nwaves){
        size_t i = (size_t)wid;
        int start = off[wid], c = cnt[wid];
        unsigned v0 = *(const unsigned*)(hs + i * 128 + lane * 2);
        float a0 = b2f((unsigned short)v0);
        float a1 = b2f((unsigned short)(v0 >> 16));
        int j = 0;
        for (; j + 8 <= c; j += 8){
            size_t s0 = (size_t)csr[start + j + 0];
            size_t s1 = (size_t)csr[start + j + 1];
            size_t s2 = (size_t)csr[start + j + 2];
            size_t s3 = (size_t)csr[start + j + 3];
            size_t s4 = (size_t)csr[start + j + 4];
            size_t s5 = (size_t)csr[start + j + 5];
            size_t s6 = (size_t)csr[start + j + 6];
            size_t s7 = (size_t)csr[start + j + 7];
            unsigned w0 = *(const unsigned*)(hs + s0 * 128 + lane * 2);
            unsigned w1 = *(const unsigned*)(hs + s1 * 128 + lane * 2);
            unsigned w2 = *(const unsigned*)(hs + s2 * 128 + lane * 2);
            unsigned w3 = *(const unsigned*)(hs + s3 * 128 + lane * 2);
            unsigned w4 = *(const unsigned*)(hs + s4 * 128 + lane * 2);
            unsigned w5 = *(const unsigned*)(hs + s5 * 128 + lane * 2);
            unsigned w6 = *(const unsigned*)(hs + s6 * 128 + lane * 2);
            unsigned w7 = *(const unsigned*)(hs + s7 * 128 + lane * 2);
            a0 += b2f((unsigned short)w0); a1 += b2f((unsigned short)(w0 >> 16));
            a0 += b2f((unsigned short)w1); a1 += b2f((unsigned short)(w1 >> 16));
            a0 += b2f((unsigned short)w2); a1 += b2f((unsigned short)(w2 >> 16));
            a0 += b2f((unsigned short)w3); a1 += b2f((unsigned short)(w3 >> 16));
            a0 += b2f((unsigned short)w4); a1 += b2f((unsigned short)(w4 >> 16));
            a0 += b2f((unsigned short)w5); a1 += b2f((unsigned short)(w5 >> 16));
            a0 += b2f((unsigned short)w6); a1 += b2f((unsigned short)(w6 >> 16));
            a0 += b2f((unsigned short)w7); a1 += b2f((unsigned short)(w7 >> 16));
        }
        for (; j < c; j++){
            size_t s = (size_t)csr[start + j];
            unsigned v = *(const unsigned*)(hs + s * 128 + lane * 2);
            a0 += b2f((unsigned short)v);
            a1 += b2f((unsigned short)(v >> 16));
        }
        float dv = dinv[wid];
        float z0 = fmaxf(fmaf(dv, a0, bb.x), 0.f);
        float z1 = fmaxf(fmaf(dv, a1, bb.y), 0.f);
        // wave-synchronous LDS round trip (no barrier: per-wave buffer)
        zrow[wband][lane * 2]     = z0;
        zrow[wband][lane * 2 + 1] = z1;
        float acc = 0.f;
        #pragma unroll 16
        for (int k = 0; k < 128; k++)
            acc = fmaf(zrow[wband][k], W2l[k * 64 + lane], acc);
        hs2[i * 64 + lane] = f2b(acc * dv);
    }
}

// ---------------- aggregation layer 2 (64 cols, wave per node, bf16 out) -------
__global__ __launch_bounds__(256) void k_agg2(const unsigned short* __restrict__ hs,
                                              const int* __restrict__ off,
                                              const int* __restrict__ cnt,
                                              const int* __restrict__ csr,
                                              const float* __restrict__ dinv,
                                              const float* __restrict__ b,
                                              unsigned short* __restrict__ z, int n){
    int wid = (blockIdx.x * 256 + threadIdx.x) >> 6;
    int lane = threadIdx.x & 63;
    if (wid >= n) return;
    size_t i = (size_t)wid;
    int start = off[wid], c = cnt[wid];
    float a = b2f(hs[i * 64 + lane]);
    int j = 0;
    for (; j + 8 <= c; j += 8){
        size_t s0 = (size_t)csr[start + j + 0];
        size_t s1 = (size_t)csr[start + j + 1];
        size_t s2 = (size_t)csr[start + j + 2];
        size_t s3 = (size_t)csr[start + j + 3];
        size_t s4 = (size_t)csr[start + j + 4];
        size_t s5 = (size_t)csr[start + j + 5];
        size_t s6 = (size_t)csr[start + j + 6];
        size_t s7 = (size_t)csr[start + j + 7];
        unsigned short h0 = hs[s0 * 64 + lane];
        unsigned short h1 = hs[s1 * 64 + lane];
        unsigned short h2 = hs[s2 * 64 + lane];
        unsigned short h3 = hs[s3 * 64 + lane];
        unsigned short h4 = hs[s4 * 64 + lane];
        unsigned short h5 = hs[s5 * 64 + lane];
        unsigned short h6 = hs[s6 * 64 + lane];
        unsigned short h7 = hs[s7 * 64 + lane];
        a += b2f(h0); a += b2f(h1); a += b2f(h2); a += b2f(h3);
        a += b2f(h4); a += b2f(h5); a += b2f(h6); a += b2f(h7);
    }
    for (; j < c; j++){
        size_t s = (size_t)csr[start + j];
        a += b2f(hs[s * 64 + lane]);
    }
    z[i * 64 + lane] = f2b(fmaf(dinv[wid], a, b[lane]));
}

// ---------------- decode: out[e] = dot(z2[s], z2[t]); z2 bf16; 2 edges/wave ----
// Grid: one 256-thread block covers 4 waves x 2 = 8 edges.
__global__ __launch_bounds__(256) void k_decode(const unsigned short* __restrict__ z,
                                                const int* __restrict__ es,
                                                const int* __restrict__ et,
                                                float* __restrict__ out, int m){
    int wv = (blockIdx.x * 256 + threadIdx.x) >> 6;
    int lane = threadIdx.x & 63;
    int e = wv * 2 + (lane >> 5);
    int hl = lane & 31;
    float p = 0.f;
    if (e < m){
        size_t s = (size_t)es[e], t2 = (size_t)et[e];
        unsigned vs = *(const unsigned*)(z + s * 64 + hl * 2);
        unsigned vt = *(const unsigned*)(z + t2 * 64 + hl * 2);
        p = b2f((unsigned short)vs) * b2f((unsigned short)vt)
          + b2f((unsigned short)(vs >> 16)) * b2f((unsigned short)(vt >> 16));
    }
    #pragma unroll
    for (int o = 16; o > 0; o >>= 1) p += __shfl_xor(p, o);
    if (hl == 0 && e < m) out[e] = p;
}

// ---------------- launcher ----------------

extern "C" void kernel_launch(void* const* d_in, const int* in_sizes, int n_in,
                              void* d_out, int out_size, void* d_ws, size_t ws_size,
                              hipStream_t stream){
    const float* x   = (const float*)d_in[0];
    const int*   ei  = (const int*)d_in[1];
    const int*   eli = (const int*)d_in[2];
    const float* W1  = (const float*)d_in[3];
    const float* b1  = (const float*)d_in[4];
    const float* W2  = (const float*)d_in[5];
    const float* b2  = (const float*)d_in[6];
    float* out = (float*)d_out;

    int N_  = in_sizes[0] / 128;
    int E_  = in_sizes[1] / 2;
    int EL_ = in_sizes[2] / 2;
    int NBINS = (N_ + 127) >> 7;           // 782 for N=100k (must be <= 1024)
    const int EPB = 8192;
    int NBLK = (E_ + EPB - 1) / EPB;       // 196 for E=1.6M

    char* w = (char*)d_ws;
    size_t o = 0;
    auto alloc = [&](size_t bytes) -> size_t {
        size_t r = o; o += (bytes + 511) & ~(size_t)511; return r;
    };
    size_t o_cnt  = alloc((size_t)N_ * 4);
    size_t o_off  = alloc((size_t)N_ * 4);
    size_t o_dinv = alloc((size_t)N_ * 4);
    size_t o_btot = alloc((size_t)NBINS * 4);
    size_t o_boff = alloc((size_t)(NBINS + 1) * 4);
    size_t o_csr  = alloc((size_t)E_ * 4);
    size_t o_wf1  = alloc(16384 * 2);
    size_t o_hs1  = alloc((size_t)N_ * 128 * 2);
    size_t o_hs2  = alloc((size_t)N_ * 64 * 2);

    int* cnt  = (int*)(w + o_cnt);
    int* off  = (int*)(w + o_off);
    float* dinv = (float*)(w + o_dinv);
    int* btot = (int*)(w + o_btot);
    int* boff = (int*)(w + o_boff);
    int* csr  = (int*)(w + o_csr);
    unsigned short* wf1 = (unsigned short*)(w + o_wf1);
    unsigned short* hs1 = (unsigned short*)(w + o_hs1);
    unsigned short* hs2 = (unsigned short*)(w + o_hs2);
    unsigned short* z2  = (unsigned short*)(w + o_hs1);  // hs1 dead after agg1g2

    // hist and part alias the hs1 region (dead before k_gemm1 writes hs1)
    int* hist = (int*)(w + o_hs1);                         // NBINS*NBLK*4 ≈ 613KB
    unsigned* part = (unsigned*)(w + o_hs1 + 4u * 1024u * 1024u);   // E*4 = 6.4MB

    const int AGG1_BLOCKS = 1024;          // 4 blocks/CU (34KB LDS), persistent
    int nwaves = AGG1_BLOCKS * 4;

    k_hist    <<<NBLK, 256, 0, stream>>>(ei + E_, hist, E_, NBINS, NBLK);
    k_binscanA<<<NBINS, 64, 0, stream>>>(hist, btot, NBLK);
    k_binscanB<<<1, 1024, 0, stream>>>(btot, boff, NBINS);
    k_scatter <<<NBLK, 256, 0, stream>>>(ei, ei + E_, hist, boff, part, E_, NBINS, NBLK);
    k_binsort <<<NBINS, 256, 0, stream>>>(part, boff, csr, cnt, off, dinv, N_, NBINS);
    k_wconv   <<<8, 256, 0, stream>>>(W1, wf1);
    k_gemm1   <<<(N_ + 63) / 64, 256, 0, stream>>>(x, wf1, dinv, hs1, N_);
    k_agg1g2  <<<AGG1_BLOCKS, 256, 0, stream>>>(hs1, off, cnt, csr, dinv, b1, W2, hs2, N_, nwaves);
    k_agg2    <<<(N_ + 3) / 4, 256, 0, stream>>>(hs2, off, cnt, csr, dinv, b2, z2, N_);
    k_decode  <<<(EL_ + 7) / 8, 256, 0, stream>>>(z2, eli, eli + EL_, out, EL_);
}

// Round 7
// 319.801 us; speedup vs baseline: 1.1426x; 1.1426x over previous
//
#include <hip/hip_runtime.h>
#include <stdint.h>

typedef __bf16 bf16x8 __attribute__((ext_vector_type(8)));
typedef float  floatx4 __attribute__((ext_vector_type(4)));

__device__ __forceinline__ unsigned short f2b(float x){
    unsigned u = __float_as_uint(x);
    u = u + 0x7FFFu + ((u >> 16) & 1u);          // RNE
    return (unsigned short)(u >> 16);
}
__device__ __forceinline__ float b2f(unsigned short h){
    return __uint_as_float(((unsigned)h) << 16);
}

// ================= CSR build: two-level counting sort (no global atomics) ====
// bin = dst >> 7 (128 nodes per bin). EPB = 8192 edges per hist/scatter block.

__global__ __launch_bounds__(256) void k_hist(const int* __restrict__ dst,
                                              int* __restrict__ hist,
                                              int E_, int nbins, int nblk){
    __shared__ int h[1024];
    int t = threadIdx.x, blk = blockIdx.x;
    for (int i = t; i < nbins; i += 256) h[i] = 0;
    __syncthreads();
    int base = blk * 8192;
    #pragma unroll
    for (int j = 0; j < 8; j++){
        int e = base + (j * 256 + t) * 4;
        if (e < E_){
            int4 d = *(const int4*)(dst + e);
            atomicAdd(&h[d.x >> 7], 1);
            atomicAdd(&h[d.y >> 7], 1);
            atomicAdd(&h[d.z >> 7], 1);
            atomicAdd(&h[d.w >> 7], 1);
        }
    }
    __syncthreads();
    for (int i = t; i < nbins; i += 256) hist[(size_t)i * nblk + blk] = h[i];
}

// per-bin exclusive scan across blocks, in place; bin totals out. 1 wave/bin.
__global__ __launch_bounds__(64) void k_binscanA(int* __restrict__ hist,
                                                 int* __restrict__ btot, int nblk){
    int bin = blockIdx.x, lane = threadIdx.x;
    int carry = 0;
    for (int base = 0; base < nblk; base += 64){
        int idx = bin * nblk + base + lane;
        bool inb = (base + lane) < nblk;
        int v = inb ? hist[idx] : 0;
        int orig = v;
        #pragma unroll
        for (int o = 1; o < 64; o <<= 1){
            int u = __shfl_up(v, o);
            if (lane >= o) v += u;
        }
        if (inb) hist[idx] = v - orig + carry;
        carry += __shfl(v, 63);
    }
    if (lane == 0) btot[bin] = carry;
}

// scan of bin totals -> binoff[0..nbins]  (requires nbins <= 1024)
__global__ __launch_bounds__(1024) void k_binscanB(const int* __restrict__ btot,
                                                   int* __restrict__ boff, int nbins){
    __shared__ int s[1024];
    int t = threadIdx.x;
    s[t] = (t < nbins) ? btot[t] : 0;
    __syncthreads();
    for (int o = 1; o < 1024; o <<= 1){
        int v = (t >= o) ? s[t - o] : 0;
        __syncthreads();
        s[t] += v;
        __syncthreads();
    }
    if (t == 0) boff[0] = 0;
    if (t < nbins) boff[t + 1] = s[t];
}

// partition edges into bin segments; positions via LDS counters only.
// packed word (UNSIGNED): (dst & 127) << 25 | src     (needs N < 2^25)
__global__ __launch_bounds__(256) void k_scatter(const int* __restrict__ src,
                                                 const int* __restrict__ dst,
                                                 const int* __restrict__ hist,
                                                 const int* __restrict__ boff,
                                                 unsigned* __restrict__ part,
                                                 int E_, int nbins, int nblk){
    __shared__ int cur[1024];
    int t = threadIdx.x, blk = blockIdx.x;
    for (int i = t; i < nbins; i += 256)
        cur[i] = boff[i] + hist[(size_t)i * nblk + blk];
    __syncthreads();
    int base = blk * 8192;
    #pragma unroll
    for (int j = 0; j < 8; j++){
        int e = base + (j * 256 + t) * 4;
        if (e < E_){
            int4 d = *(const int4*)(dst + e);
            int4 s = *(const int4*)(src + e);
            int p0 = atomicAdd(&cur[d.x >> 7], 1);
            part[p0] = ((unsigned)(d.x & 127) << 25) | (unsigned)s.x;
            int p1 = atomicAdd(&cur[d.y >> 7], 1);
            part[p1] = ((unsigned)(d.y & 127) << 25) | (unsigned)s.y;
            int p2 = atomicAdd(&cur[d.z >> 7], 1);
            part[p2] = ((unsigned)(d.z & 127) << 25) | (unsigned)s.z;
            int p3 = atomicAdd(&cur[d.w >> 7], 1);
            part[p3] = ((unsigned)(d.w & 127) << 25) | (unsigned)s.w;
        }
    }
}

// one block per bin: local count/scan/rank in LDS; coalesced csr write.
// Also emits cnt[node], off[node], dinv[node] for the bin's 128 nodes.
__global__ __launch_bounds__(256) void k_binsort(const unsigned* __restrict__ part,
                                                 const int* __restrict__ boff,
                                                 int* __restrict__ csr,
                                                 int* __restrict__ cnt,
                                                 int* __restrict__ off,
                                                 float* __restrict__ dinv,
                                                 int n, int nbins){
    int b = blockIdx.x, t = threadIdx.x;
    int s0 = boff[b], s1 = boff[b + 1], len = s1 - s0;
    __shared__ int cl[128], sc[128], cur[128];
    __shared__ unsigned buf[4096], outb[4096];
    if (t < 128){ cl[t] = 0; cur[t] = 0; }
    __syncthreads();
    if (len <= 4096){
        for (int i = t; i < len; i += 256) buf[i] = part[s0 + i];
        __syncthreads();
        for (int i = t; i < len; i += 256) atomicAdd(&cl[buf[i] >> 25], 1);
        __syncthreads();
        if (t < 128) sc[t] = cl[t];
        __syncthreads();
        for (int o = 1; o < 128; o <<= 1){
            int v = 0;
            if (t < 128 && t >= o) v = sc[t - o];
            __syncthreads();
            if (t < 128) sc[t] += v;
            __syncthreads();
        }
        for (int i = t; i < len; i += 256){
            unsigned w = buf[i];
            int nd = (int)(w >> 25);
            int p = (sc[nd] - cl[nd]) + atomicAdd(&cur[nd], 1);
            outb[p] = w & 0x1FFFFFFu;
        }
        __syncthreads();
        for (int i = t; i < len; i += 256) csr[s0 + i] = (int)outb[i];
    } else {
        // fallback (never expected at these sizes): two global passes
        for (int i = t; i < len; i += 256) atomicAdd(&cl[part[s0 + i] >> 25], 1);
        __syncthreads();
        if (t < 128) sc[t] = cl[t];
        __syncthreads();
        for (int o = 1; o < 128; o <<= 1){
            int v = 0;
            if (t < 128 && t >= o) v = sc[t - o];
            __syncthreads();
            if (t < 128) sc[t] += v;
            __syncthreads();
        }
        for (int i = t; i < len; i += 256){
            unsigned w = part[s0 + i];
            int nd = (int)(w >> 25);
            int p = (sc[nd] - cl[nd]) + atomicAdd(&cur[nd], 1);
            csr[s0 + p] = (int)(w & 0x1FFFFFFu);
        }
    }
    if (t < 128){
        int node = b * 128 + t;
        if (node < n){
            cnt[node] = cl[t];
            off[node] = s0 + (sc[t] - cl[t]);
            dinv[node] = rsqrtf((float)cl[t] + 1.0f);
        }
    }
}

// -------- weight prep: W1 -> MFMA B-frag order; W2 -> packed bf16 pairs --------
// W2p[kp*64 + lane] packs (W2[2kp][lane], W2[2kp+1][lane]) as 2 bf16.
__global__ __launch_bounds__(256) void k_wconv(const float* __restrict__ W1,
                                               const float* __restrict__ W2,
                                               unsigned short* __restrict__ wf1,
                                               unsigned* __restrict__ w2p){
    int f = blockIdx.x * 256 + threadIdx.x;
    if (f < 2048){
        int lane = f & 63;
        int ctkc = f >> 6;
        int kc = ctkc & 3, ct = ctkc >> 2;
        int col = ct * 16 + (lane & 15);
        int k0  = kc * 32 + (lane >> 4) * 8;
        unsigned short* d = wf1 + (size_t)f * 8;
        #pragma unroll
        for (int j = 0; j < 8; j++) d[j] = f2b(W1[(k0 + j) * 128 + col]);
    } else if (f < 2048 + 4096){
        int lf = f - 2048;
        int kp = lf >> 6, lane = lf & 63;
        unsigned lo = f2b(W2[(2 * kp) * 64 + lane]);
        unsigned hi = f2b(W2[(2 * kp + 1) * 64 + lane]);
        w2p[lf] = lo | (hi << 16);
    }
}

// ---------------- GEMM1: hs1 = bf16( (x @ W1) * dinv[row] ) ----------------
__global__ __launch_bounds__(256) void k_gemm1(const float* __restrict__ x,
                                               const unsigned short* __restrict__ wf,
                                               const float* __restrict__ dinv,
                                               unsigned short* __restrict__ hs, int n){
    __shared__ unsigned short Wl[16384];
    __shared__ unsigned short Al[64 * 136];
    int t = threadIdx.x;
    long rowBase = (long)blockIdx.x * 64;
    {
        const uint4* s4 = (const uint4*)wf;
        uint4* d4 = (uint4*)Wl;
        #pragma unroll
        for (int i = 0; i < 8; i++) d4[t + i * 256] = s4[t + i * 256];
    }
    {
        const float4* xs = (const float4*)(x + rowBase * 128);
        #pragma unroll
        for (int k = 0; k < 8; k++){
            int i = t + k * 256;
            int r = i >> 5, c4 = (i & 31) << 2;
            float4 v = make_float4(0.f, 0.f, 0.f, 0.f);
            if (rowBase + r < n) v = xs[i];
            unsigned lo = (unsigned)f2b(v.x) | ((unsigned)f2b(v.y) << 16);
            unsigned hi = (unsigned)f2b(v.z) | ((unsigned)f2b(v.w) << 16);
            *(uint2*)&Al[r * 136 + c4] = make_uint2(lo, hi);
        }
    }
    __syncthreads();
    int w = t >> 6, lane = t & 63, lr = lane & 15, q = lane >> 4;
    floatx4 zero = {0.f, 0.f, 0.f, 0.f};
    floatx4 acc[8];
    #pragma unroll
    for (int ct = 0; ct < 8; ct++) acc[ct] = zero;
    #pragma unroll
    for (int kc = 0; kc < 4; kc++){
        bf16x8 af = *(const bf16x8*)&Al[(w * 16 + lr) * 136 + kc * 32 + q * 8];
        #pragma unroll
        for (int ct = 0; ct < 8; ct++){
            bf16x8 bf = *(const bf16x8*)&Wl[((ct * 4 + kc) * 64 + lane) * 8];
            acc[ct] = __builtin_amdgcn_mfma_f32_16x16x32_bf16(af, bf, acc[ct], 0, 0, 0);
        }
    }
    long r0 = rowBase + w * 16 + q * 4;
    #pragma unroll
    for (int r = 0; r < 4; r++){
        long row = r0 + r;
        if (row >= n) continue;
        float dv = dinv[row];
        unsigned short* orow = hs + row * 128 + lr;
        #pragma unroll
        for (int ct = 0; ct < 8; ct++) orow[ct * 16] = f2b(acc[ct][r] * dv);
    }
}

// ---- fused agg1 + gemm2: hs2[i] = bf16( (relu(dinv_i*(sum hs1[src]+hs1[i])+b1) @ W2) * dinv_i )
// wave per node (grid-stride, 2048 persistent blocks = 8 blocks/CU, 32 waves/CU);
// W2 staged in LDS as packed bf16 pairs (16KB) -> total LDS ~18.5KB/block.
__global__ __launch_bounds__(256) void k_agg1g2(const unsigned short* __restrict__ hs,
                                                const int* __restrict__ off,
                                                const int* __restrict__ cnt,
                                                const int* __restrict__ csr,
                                                const float* __restrict__ dinv,
                                                const float* __restrict__ b1,
                                                const unsigned* __restrict__ w2p,
                                                unsigned short* __restrict__ hs2,
                                                int n, int nwaves){
    __shared__ unsigned W2l[4096];     // 16 KB packed bf16 pairs [kp][lane]
    __shared__ float zrow[4][128];     // 2 KB, one row per wave
    int t = threadIdx.x;
    {
        const uint4* w4 = (const uint4*)w2p;
        uint4* d4 = (uint4*)W2l;
        #pragma unroll
        for (int i = 0; i < 4; i++) d4[t + i * 256] = w4[t + i * 256];
    }
    __syncthreads();
    int wband = t >> 6, lane = t & 63;
    float2 bb = ((const float2*)b1)[lane];
    for (int wid = blockIdx.x * 4 + wband; wid < n; wid += nwaves){
        size_t i = (size_t)wid;
        int start = off[wid], c = cnt[wid];
        unsigned v0 = *(const unsigned*)(hs + i * 128 + lane * 2);
        float a0 = b2f((unsigned short)v0);
        float a1 = b2f((unsigned short)(v0 >> 16));
        int j = 0;
        for (; j + 8 <= c; j += 8){
            size_t s0 = (size_t)csr[start + j + 0];
            size_t s1 = (size_t)csr[start + j + 1];
            size_t s2 = (size_t)csr[start + j + 2];
            size_t s3 = (size_t)csr[start + j + 3];
            size_t s4 = (size_t)csr[start + j + 4];
            size_t s5 = (size_t)csr[start + j + 5];
            size_t s6 = (size_t)csr[start + j + 6];
            size_t s7 = (size_t)csr[start + j + 7];
            unsigned w0 = *(const unsigned*)(hs + s0 * 128 + lane * 2);
            unsigned w1 = *(const unsigned*)(hs + s1 * 128 + lane * 2);
            unsigned w2 = *(const unsigned*)(hs + s2 * 128 + lane * 2);
            unsigned w3 = *(const unsigned*)(hs + s3 * 128 + lane * 2);
            unsigned w4 = *(const unsigned*)(hs + s4 * 128 + lane * 2);
            unsigned w5 = *(const unsigned*)(hs + s5 * 128 + lane * 2);
            unsigned w6 = *(const unsigned*)(hs + s6 * 128 + lane * 2);
            unsigned w7 = *(const unsigned*)(hs + s7 * 128 + lane * 2);
            a0 += b2f((unsigned short)w0); a1 += b2f((unsigned short)(w0 >> 16));
            a0 += b2f((unsigned short)w1); a1 += b2f((unsigned short)(w1 >> 16));
            a0 += b2f((unsigned short)w2); a1 += b2f((unsigned short)(w2 >> 16));
            a0 += b2f((unsigned short)w3); a1 += b2f((unsigned short)(w3 >> 16));
            a0 += b2f((unsigned short)w4); a1 += b2f((unsigned short)(w4 >> 16));
            a0 += b2f((unsigned short)w5); a1 += b2f((unsigned short)(w5 >> 16));
            a0 += b2f((unsigned short)w6); a1 += b2f((unsigned short)(w6 >> 16));
            a0 += b2f((unsigned short)w7); a1 += b2f((unsigned short)(w7 >> 16));
        }
        for (; j < c; j++){
            size_t s = (size_t)csr[start + j];
            unsigned v = *(const unsigned*)(hs + s * 128 + lane * 2);
            a0 += b2f((unsigned short)v);
            a1 += b2f((unsigned short)(v >> 16));
        }
        float dv = dinv[wid];
        float z0 = fmaxf(fmaf(dv, a0, bb.x), 0.f);
        float z1 = fmaxf(fmaf(dv, a1, bb.y), 0.f);
        // wave-synchronous LDS round trip (no barrier: per-wave buffer)
        zrow[wband][lane * 2]     = z0;
        zrow[wband][lane * 2 + 1] = z1;
        float acc = 0.f;
        #pragma unroll 8
        for (int kp = 0; kp < 64; kp++){
            unsigned wv = W2l[kp * 64 + lane];
            float2 zz = *(const float2*)&zrow[wband][kp * 2];
            acc = fmaf(zz.x, b2f((unsigned short)wv), acc);
            acc = fmaf(zz.y, b2f((unsigned short)(wv >> 16)), acc);
        }
        hs2[i * 64 + lane] = f2b(acc * dv);
    }
}

// ---------------- aggregation layer 2 (64 cols, wave per node, bf16 out) -------
__global__ __launch_bounds__(256) void k_agg2(const unsigned short* __restrict__ hs,
                                              const int* __restrict__ off,
                                              const int* __restrict__ cnt,
                                              const int* __restrict__ csr,
                                              const float* __restrict__ dinv,
                                              const float* __restrict__ b,
                                              unsigned short* __restrict__ z, int n){
    int wid = (blockIdx.x * 256 + threadIdx.x) >> 6;
    int lane = threadIdx.x & 63;
    if (wid >= n) return;
    size_t i = (size_t)wid;
    int start = off[wid], c = cnt[wid];
    float a = b2f(hs[i * 64 + lane]);
    int j = 0;
    for (; j + 8 <= c; j += 8){
        size_t s0 = (size_t)csr[start + j + 0];
        size_t s1 = (size_t)csr[start + j + 1];
        size_t s2 = (size_t)csr[start + j + 2];
        size_t s3 = (size_t)csr[start + j + 3];
        size_t s4 = (size_t)csr[start + j + 4];
        size_t s5 = (size_t)csr[start + j + 5];
        size_t s6 = (size_t)csr[start + j + 6];
        size_t s7 = (size_t)csr[start + j + 7];
        unsigned short h0 = hs[s0 * 64 + lane];
        unsigned short h1 = hs[s1 * 64 + lane];
        unsigned short h2 = hs[s2 * 64 + lane];
        unsigned short h3 = hs[s3 * 64 + lane];
        unsigned short h4 = hs[s4 * 64 + lane];
        unsigned short h5 = hs[s5 * 64 + lane];
        unsigned short h6 = hs[s6 * 64 + lane];
        unsigned short h7 = hs[s7 * 64 + lane];
        a += b2f(h0); a += b2f(h1); a += b2f(h2); a += b2f(h3);
        a += b2f(h4); a += b2f(h5); a += b2f(h6); a += b2f(h7);
    }
    for (; j < c; j++){
        size_t s = (size_t)csr[start + j];
        a += b2f(hs[s * 64 + lane]);
    }
    z[i * 64 + lane] = f2b(fmaf(dinv[wid], a, b[lane]));
}

// ---------------- decode: out[e] = dot(z2[s], z2[t]); z2 bf16; 2 edges/wave ----
// Grid: one 256-thread block covers 4 waves x 2 = 8 edges.
__global__ __launch_bounds__(256) void k_decode(const unsigned short* __restrict__ z,
                                                const int* __restrict__ es,
                                                const int* __restrict__ et,
                                                float* __restrict__ out, int m){
    int wv = (blockIdx.x * 256 + threadIdx.x) >> 6;
    int lane = threadIdx.x & 63;
    int e = wv * 2 + (lane >> 5);
    int hl = lane & 31;
    float p = 0.f;
    if (e < m){
        size_t s = (size_t)es[e], t2 = (size_t)et[e];
        unsigned vs = *(const unsigned*)(z + s * 64 + hl * 2);
        unsigned vt = *(const unsigned*)(z + t2 * 64 + hl * 2);
        p = b2f((unsigned short)vs) * b2f((unsigned short)vt)
          + b2f((unsigned short)(vs >> 16)) * b2f((unsigned short)(vt >> 16));
    }
    #pragma unroll
    for (int o = 16; o > 0; o >>= 1) p += __shfl_xor(p, o);
    if (hl == 0 && e < m) out[e] = p;
}

// ---------------- launcher ----------------

extern "C" void kernel_launch(void* const* d_in, const int* in_sizes, int n_in,
                              void* d_out, int out_size, void* d_ws, size_t ws_size,
                              hipStream_t stream){
    const float* x   = (const float*)d_in[0];
    const int*   ei  = (const int*)d_in[1];
    const int*   eli = (const int*)d_in[2];
    const float* W1  = (const float*)d_in[3];
    const float* b1  = (const float*)d_in[4];
    const float* W2  = (const float*)d_in[5];
    const float* b2  = (const float*)d_in[6];
    float* out = (float*)d_out;

    int N_  = in_sizes[0] / 128;
    int E_  = in_sizes[1] / 2;
    int EL_ = in_sizes[2] / 2;
    int NBINS = (N_ + 127) >> 7;           // 782 for N=100k (must be <= 1024)
    const int EPB = 8192;
    int NBLK = (E_ + EPB - 1) / EPB;       // 196 for E=1.6M

    char* w = (char*)d_ws;
    size_t o = 0;
    auto alloc = [&](size_t bytes) -> size_t {
        size_t r = o; o += (bytes + 511) & ~(size_t)511; return r;
    };
    size_t o_cnt  = alloc((size_t)N_ * 4);
    size_t o_off  = alloc((size_t)N_ * 4);
    size_t o_dinv = alloc((size_t)N_ * 4);
    size_t o_btot = alloc((size_t)NBINS * 4);
    size_t o_boff = alloc((size_t)(NBINS + 1) * 4);
    size_t o_csr  = alloc((size_t)E_ * 4);
    size_t o_wf1  = alloc(16384 * 2);
    size_t o_w2p  = alloc(4096 * 4);
    size_t o_hs1  = alloc((size_t)N_ * 128 * 2);
    size_t o_hs2  = alloc((size_t)N_ * 64 * 2);

    int* cnt  = (int*)(w + o_cnt);
    int* off  = (int*)(w + o_off);
    float* dinv = (float*)(w + o_dinv);
    int* btot = (int*)(w + o_btot);
    int* boff = (int*)(w + o_boff);
    int* csr  = (int*)(w + o_csr);
    unsigned short* wf1 = (unsigned short*)(w + o_wf1);
    unsigned* w2p = (unsigned*)(w + o_w2p);
    unsigned short* hs1 = (unsigned short*)(w + o_hs1);
    unsigned short* hs2 = (unsigned short*)(w + o_hs2);
    unsigned short* z2  = (unsigned short*)(w + o_hs1);  // hs1 dead after agg1g2

    // hist and part alias the hs1 region (dead before k_gemm1 writes hs1)
    int* hist = (int*)(w + o_hs1);                         // NBINS*NBLK*4 ≈ 613KB
    unsigned* part = (unsigned*)(w + o_hs1 + 4u * 1024u * 1024u);   // E*4 = 6.4MB

    const int AGG1_BLOCKS = 2048;          // 8 blocks/CU (18.5KB LDS) -> 32 waves/CU
    int nwaves = AGG1_BLOCKS * 4;

    k_hist    <<<NBLK, 256, 0, stream>>>(ei + E_, hist, E_, NBINS, NBLK);
    k_binscanA<<<NBINS, 64, 0, stream>>>(hist, btot, NBLK);
    k_binscanB<<<1, 1024, 0, stream>>>(btot, boff, NBINS);
    k_scatter <<<NBLK, 256, 0, stream>>>(ei, ei + E_, hist, boff, part, E_, NBINS, NBLK);
    k_binsort <<<NBINS, 256, 0, stream>>>(part, boff, csr, cnt, off, dinv, N_, NBINS);
    k_wconv   <<<24, 256, 0, stream>>>(W1, W2, wf1, w2p);
    k_gemm1   <<<(N_ + 63) / 64, 256, 0, stream>>>(x, wf1, dinv, hs1, N_);
    k_agg1g2  <<<AGG1_BLOCKS, 256, 0, stream>>>(hs1, off, cnt, csr, dinv, b1, w2p, hs2, N_, nwaves);
    k_agg2    <<<(N_ + 3) / 4, 256, 0, stream>>>(hs2, off, cnt, csr, dinv, b2, z2, N_);
    k_decode  <<<(EL_ + 7) / 8, 256, 0, stream>>>(z2, eli, eli + EL_, out, EL_);
}

// Round 9
// 279.485 us; speedup vs baseline: 1.3074x; 1.1443x over previous
//
#include <hip/hip_runtime.h>
#include <stdint.h>

typedef __bf16 bf16x8 __attribute__((ext_vector_type(8)));
typedef float  floatx4 __attribute__((ext_vector_type(4)));
typedef __fp16 h2 __attribute__((ext_vector_type(2)));

__device__ __forceinline__ unsigned short f2b(float x){
    unsigned u = __float_as_uint(x);
    u = u + 0x7FFFu + ((u >> 16) & 1u);          // RNE
    return (unsigned short)(u >> 16);
}
__device__ __forceinline__ float b2f(unsigned short h){
    return __uint_as_float(((unsigned)h) << 16);
}

// ================= CSR build: reservation counting sort (2 dispatches) =======
// bin = dst >> 7 (128 nodes/bin). Slab capacity 4096/bin (mean 2046, sigma~45).

// per-block LDS hist -> one global atomicAdd per (block,bin) reserves slab
// range -> write pass places edges via LDS cursors. No per-edge global atomics.
__global__ __launch_bounds__(256) void k_scatter2(const int* __restrict__ src,
                                                  const int* __restrict__ dst,
                                                  int* __restrict__ gcur,
                                                  unsigned* __restrict__ slab,
                                                  int E_, int nbins){
    __shared__ int h[1024];
    int t = threadIdx.x, blk = blockIdx.x;
    for (int i = t; i < nbins; i += 256) h[i] = 0;
    __syncthreads();
    int base = blk * 8192;
    #pragma unroll
    for (int j = 0; j < 8; j++){
        int e = base + (j * 256 + t) * 4;
        if (e < E_){
            int4 d = *(const int4*)(dst + e);
            atomicAdd(&h[d.x >> 7], 1);
            atomicAdd(&h[d.y >> 7], 1);
            atomicAdd(&h[d.z >> 7], 1);
            atomicAdd(&h[d.w >> 7], 1);
        }
    }
    __syncthreads();
    // reserve: h[i] becomes this block's base cursor within bin i's slab
    for (int i = t; i < nbins; i += 256){
        int hv = h[i];
        h[i] = hv ? atomicAdd(&gcur[i], hv) : 0;
    }
    __syncthreads();
    #pragma unroll
    for (int j = 0; j < 8; j++){
        int e = base + (j * 256 + t) * 4;
        if (e < E_){
            int4 d = *(const int4*)(dst + e);
            int4 s = *(const int4*)(src + e);
            int p0 = atomicAdd(&h[d.x >> 7], 1);
            slab[(size_t)(d.x >> 7) * 4096 + p0] = ((unsigned)(d.x & 127) << 25) | (unsigned)s.x;
            int p1 = atomicAdd(&h[d.y >> 7], 1);
            slab[(size_t)(d.y >> 7) * 4096 + p1] = ((unsigned)(d.y & 127) << 25) | (unsigned)s.y;
            int p2 = atomicAdd(&h[d.z >> 7], 1);
            slab[(size_t)(d.z >> 7) * 4096 + p2] = ((unsigned)(d.z & 127) << 25) | (unsigned)s.z;
            int p3 = atomicAdd(&h[d.w >> 7], 1);
            slab[(size_t)(d.w >> 7) * 4096 + p3] = ((unsigned)(d.w & 127) << 25) | (unsigned)s.w;
        }
    }
}

// scan of bin totals -> boff[0..nbins]  (requires nbins <= 1024)
__global__ __launch_bounds__(1024) void k_binscanB(const int* __restrict__ btot,
                                                   int* __restrict__ boff, int nbins){
    __shared__ int s[1024];
    int t = threadIdx.x;
    s[t] = (t < nbins) ? btot[t] : 0;
    __syncthreads();
    for (int o = 1; o < 1024; o <<= 1){
        int v = (t >= o) ? s[t - o] : 0;
        __syncthreads();
        s[t] += v;
        __syncthreads();
    }
    if (t == 0) boff[0] = 0;
    if (t < nbins) boff[t + 1] = s[t];
}

// one block per bin: local count/scan/rank in LDS; coalesced csr write.
// Also emits cnt[node], off[node], dinv[node] for the bin's 128 nodes.
__global__ __launch_bounds__(256) void k_binsort(const unsigned* __restrict__ slab,
                                                 const int* __restrict__ boff,
                                                 int* __restrict__ csr,
                                                 int* __restrict__ cnt,
                                                 int* __restrict__ off,
                                                 float* __restrict__ dinv,
                                                 int n, int nbins){
    int b = blockIdx.x, t = threadIdx.x;
    int s0 = boff[b], len = boff[b + 1] - s0;
    if (len > 4096) len = 4096;    // impossible at these sizes; guards LDS OOB
    const unsigned* seg = slab + (size_t)b * 4096;
    __shared__ int cl[128], sc[128], cur[128];
    __shared__ unsigned buf[4096], outb[4096];
    if (t < 128){ cl[t] = 0; cur[t] = 0; }
    __syncthreads();
    for (int i = t; i < len; i += 256) buf[i] = seg[i];
    __syncthreads();
    for (int i = t; i < len; i += 256) atomicAdd(&cl[buf[i] >> 25], 1);
    __syncthreads();
    if (t < 128) sc[t] = cl[t];
    __syncthreads();
    for (int o = 1; o < 128; o <<= 1){
        int v = 0;
        if (t < 128 && t >= o) v = sc[t - o];
        __syncthreads();
        if (t < 128) sc[t] += v;
        __syncthreads();
    }
    for (int i = t; i < len; i += 256){
        unsigned w = buf[i];
        int nd = (int)(w >> 25);
        int p = (sc[nd] - cl[nd]) + atomicAdd(&cur[nd], 1);
        outb[p] = w & 0x1FFFFFFu;
    }
    __syncthreads();
    for (int i = t; i < len; i += 256) csr[s0 + i] = (int)outb[i];
    if (t < 128){
        int node = b * 128 + t;
        if (node < n){
            cnt[node] = cl[t];
            off[node] = s0 + (sc[t] - cl[t]);
            dinv[node] = rsqrtf((float)cl[t] + 1.0f);
        }
    }
}

// -------- weight prep: W1 -> MFMA B-frag order; W2 -> packed f16 pairs --------
// w2p[kp*64 + lane] packs (W2[2kp][lane], W2[2kp+1][lane]) as half2.
__global__ __launch_bounds__(256) void k_wconv(const float* __restrict__ W1,
                                               const float* __restrict__ W2,
                                               unsigned short* __restrict__ wf1,
                                               unsigned* __restrict__ w2p){
    int f = blockIdx.x * 256 + threadIdx.x;
    if (f < 2048){
        int lane = f & 63;
        int ctkc = f >> 6;
        int kc = ctkc & 3, ct = ctkc >> 2;
        int col = ct * 16 + (lane & 15);
        int k0  = kc * 32 + (lane >> 4) * 8;
        unsigned short* d = wf1 + (size_t)f * 8;
        #pragma unroll
        for (int j = 0; j < 8; j++) d[j] = f2b(W1[(k0 + j) * 128 + col]);
    } else if (f < 2048 + 4096){
        int lf = f - 2048;
        int kp = lf >> 6, lane = lf & 63;
        h2 p = __builtin_amdgcn_cvt_pkrtz(W2[(2 * kp) * 64 + lane],
                                          W2[(2 * kp + 1) * 64 + lane]);
        w2p[lf] = __builtin_bit_cast(unsigned, p);
    }
}

// ---------------- GEMM1: hs1 = bf16( (x @ W1) * dinv[row] ) ----------------
__global__ __launch_bounds__(256) void k_gemm1(const float* __restrict__ x,
                                               const unsigned short* __restrict__ wf,
                                               const float* __restrict__ dinv,
                                               unsigned short* __restrict__ hs, int n){
    __shared__ unsigned short Wl[16384];
    __shared__ unsigned short Al[64 * 136];
    int t = threadIdx.x;
    long rowBase = (long)blockIdx.x * 64;
    {
        const uint4* s4 = (const uint4*)wf;
        uint4* d4 = (uint4*)Wl;
        #pragma unroll
        for (int i = 0; i < 8; i++) d4[t + i * 256] = s4[t + i * 256];
    }
    {
        const float4* xs = (const float4*)(x + rowBase * 128);
        #pragma unroll
        for (int k = 0; k < 8; k++){
            int i = t + k * 256;
            int r = i >> 5, c4 = (i & 31) << 2;
            float4 v = make_float4(0.f, 0.f, 0.f, 0.f);
            if (rowBase + r < n) v = xs[i];
            unsigned lo = (unsigned)f2b(v.x) | ((unsigned)f2b(v.y) << 16);
            unsigned hi = (unsigned)f2b(v.z) | ((unsigned)f2b(v.w) << 16);
            *(uint2*)&Al[r * 136 + c4] = make_uint2(lo, hi);
        }
    }
    __syncthreads();
    int w = t >> 6, lane = t & 63, lr = lane & 15, q = lane >> 4;
    floatx4 zero = {0.f, 0.f, 0.f, 0.f};
    floatx4 acc[8];
    #pragma unroll
    for (int ct = 0; ct < 8; ct++) acc[ct] = zero;
    #pragma unroll
    for (int kc = 0; kc < 4; kc++){
        bf16x8 af = *(const bf16x8*)&Al[(w * 16 + lr) * 136 + kc * 32 + q * 8];
        #pragma unroll
        for (int ct = 0; ct < 8; ct++){
            bf16x8 bf = *(const bf16x8*)&Wl[((ct * 4 + kc) * 64 + lane) * 8];
            acc[ct] = __builtin_amdgcn_mfma_f32_16x16x32_bf16(af, bf, acc[ct], 0, 0, 0);
        }
    }
    long r0 = rowBase + w * 16 + q * 4;
    #pragma unroll
    for (int r = 0; r < 4; r++){
        long row = r0 + r;
        if (row >= n) continue;
        float dv = dinv[row];
        unsigned short* orow = hs + row * 128 + lr;
        #pragma unroll
        for (int ct = 0; ct < 8; ct++) orow[ct * 16] = f2b(acc[ct][r] * dv);
    }
}

// ---- fused agg1 + gemm2: hs2[i] = bf16( (relu(dinv_i*(sum hs1[src]+hs1[i])+b1) @ W2) * dinv_i )
// wave per node (grid-stride, 2048 persistent blocks); projection via
// v_dot2_f32_f16 on packed f16 pairs, 2 independent accumulator chains.
__global__ __launch_bounds__(256) void k_agg1g2(const unsigned short* __restrict__ hs,
                                                const int* __restrict__ off,
                                                const int* __restrict__ cnt,
                                                const int* __restrict__ csr,
                                                const float* __restrict__ dinv,
                                                const float* __restrict__ b1,
                                                const unsigned* __restrict__ w2p,
                                                unsigned short* __restrict__ hs2,
                                                int n, int nwaves){
    __shared__ unsigned W2l[4096];     // 16 KB packed half2 [kp][lane]
    __shared__ unsigned zp[4][64];     // packed half2 z row per wave
    int t = threadIdx.x;
    {
        const uint4* w4 = (const uint4*)w2p;
        uint4* d4 = (uint4*)W2l;
        #pragma unroll
        for (int i = 0; i < 4; i++) d4[t + i * 256] = w4[t + i * 256];
    }
    __syncthreads();
    int wband = t >> 6, lane = t & 63;
    float2 bb = ((const float2*)b1)[lane];
    for (int wid = blockIdx.x * 4 + wband; wid < n; wid += nwaves){
        size_t i = (size_t)wid;
        int start = off[wid], c = cnt[wid];
        unsigned v0 = *(const unsigned*)(hs + i * 128 + lane * 2);
        float a0 = b2f((unsigned short)v0);
        float a1 = b2f((unsigned short)(v0 >> 16));
        int j = 0;
        for (; j + 8 <= c; j += 8){
            size_t s0 = (size_t)csr[start + j + 0];
            size_t s1 = (size_t)csr[start + j + 1];
            size_t s2 = (size_t)csr[start + j + 2];
            size_t s3 = (size_t)csr[start + j + 3];
            size_t s4 = (size_t)csr[start + j + 4];
            size_t s5 = (size_t)csr[start + j + 5];
            size_t s6 = (size_t)csr[start + j + 6];
            size_t s7 = (size_t)csr[start + j + 7];
            unsigned w0 = *(const unsigned*)(hs + s0 * 128 + lane * 2);
            unsigned w1 = *(const unsigned*)(hs + s1 * 128 + lane * 2);
            unsigned w2 = *(const unsigned*)(hs + s2 * 128 + lane * 2);
            unsigned w3 = *(const unsigned*)(hs + s3 * 128 + lane * 2);
            unsigned w4 = *(const unsigned*)(hs + s4 * 128 + lane * 2);
            unsigned w5 = *(const unsigned*)(hs + s5 * 128 + lane * 2);
            unsigned w6 = *(const unsigned*)(hs + s6 * 128 + lane * 2);
            unsigned w7 = *(const unsigned*)(hs + s7 * 128 + lane * 2);
            a0 += b2f((unsigned short)w0); a1 += b2f((unsigned short)(w0 >> 16));
            a0 += b2f((unsigned short)w1); a1 += b2f((unsigned short)(w1 >> 16));
            a0 += b2f((unsigned short)w2); a1 += b2f((unsigned short)(w2 >> 16));
            a0 += b2f((unsigned short)w3); a1 += b2f((unsigned short)(w3 >> 16));
            a0 += b2f((unsigned short)w4); a1 += b2f((unsigned short)(w4 >> 16));
            a0 += b2f((unsigned short)w5); a1 += b2f((unsigned short)(w5 >> 16));
            a0 += b2f((unsigned short)w6); a1 += b2f((unsigned short)(w6 >> 16));
            a0 += b2f((unsigned short)w7); a1 += b2f((unsigned short)(w7 >> 16));
        }
        for (; j < c; j++){
            size_t s = (size_t)csr[start + j];
            unsigned v = *(const unsigned*)(hs + s * 128 + lane * 2);
            a0 += b2f((unsigned short)v);
            a1 += b2f((unsigned short)(v >> 16));
        }
        float dv = dinv[wid];
        float z0 = fmaxf(fmaf(dv, a0, bb.x), 0.f);
        float z1 = fmaxf(fmaf(dv, a1, bb.y), 0.f);
        // wave-synchronous LDS round trip (per-wave buffer, no barrier)
        zp[wband][lane] = __builtin_bit_cast(unsigned, __builtin_amdgcn_cvt_pkrtz(z0, z1));
        float acc0 = 0.f, acc1 = 0.f;
        #pragma unroll 8
        for (int kp = 0; kp < 64; kp += 2){
            h2 wa = __builtin_bit_cast(h2, W2l[kp * 64 + lane]);
            h2 wb = __builtin_bit_cast(h2, W2l[(kp + 1) * 64 + lane]);
            h2 za = __builtin_bit_cast(h2, zp[wband][kp]);
            h2 zb = __builtin_bit_cast(h2, zp[wband][kp + 1]);
            acc0 = __builtin_amdgcn_fdot2(za, wa, acc0, false);
            acc1 = __builtin_amdgcn_fdot2(zb, wb, acc1, false);
        }
        hs2[i * 64 + lane] = f2b((acc0 + acc1) * dv);
    }
}

// -------- aggregation layer 2: 2 nodes/wave (half-wave each), dword loads ------
__global__ __launch_bounds__(256) void k_agg2(const unsigned short* __restrict__ hs,
                                              const int* __restrict__ off,
                                              const int* __restrict__ cnt,
                                              const int* __restrict__ csr,
                                              const float* __restrict__ dinv,
                                              const float* __restrict__ b,
                                              unsigned short* __restrict__ z, int n){
    int wv = (blockIdx.x * 256 + threadIdx.x) >> 6;
    int lane = threadIdx.x & 63;
    int half = lane >> 5, hl = lane & 31;
    int node = wv * 2 + half;
    if (node >= n) return;
    size_t i = (size_t)node;
    int start = off[node], c = cnt[node];
    unsigned v0 = *(const unsigned*)(hs + i * 64 + hl * 2);
    float a0 = b2f((unsigned short)v0);
    float a1 = b2f((unsigned short)(v0 >> 16));
    int j = 0;
    for (; j + 8 <= c; j += 8){
        size_t s0 = (size_t)csr[start + j + 0];
        size_t s1 = (size_t)csr[start + j + 1];
        size_t s2 = (size_t)csr[start + j + 2];
        size_t s3 = (size_t)csr[start + j + 3];
        size_t s4 = (size_t)csr[start + j + 4];
        size_t s5 = (size_t)csr[start + j + 5];
        size_t s6 = (size_t)csr[start + j + 6];
        size_t s7 = (size_t)csr[start + j + 7];
        unsigned w0 = *(const unsigned*)(hs + s0 * 64 + hl * 2);
        unsigned w1 = *(const unsigned*)(hs + s1 * 64 + hl * 2);
        unsigned w2 = *(const unsigned*)(hs + s2 * 64 + hl * 2);
        unsigned w3 = *(const unsigned*)(hs + s3 * 64 + hl * 2);
        unsigned w4 = *(const unsigned*)(hs + s4 * 64 + hl * 2);
        unsigned w5 = *(const unsigned*)(hs + s5 * 64 + hl * 2);
        unsigned w6 = *(const unsigned*)(hs + s6 * 64 + hl * 2);
        unsigned w7 = *(const unsigned*)(hs + s7 * 64 + hl * 2);
        a0 += b2f((unsigned short)w0); a1 += b2f((unsigned short)(w0 >> 16));
        a0 += b2f((unsigned short)w1); a1 += b2f((unsigned short)(w1 >> 16));
        a0 += b2f((unsigned short)w2); a1 += b2f((unsigned short)(w2 >> 16));
        a0 += b2f((unsigned short)w3); a1 += b2f((unsigned short)(w3 >> 16));
        a0 += b2f((unsigned short)w4); a1 += b2f((unsigned short)(w4 >> 16));
        a0 += b2f((unsigned short)w5); a1 += b2f((unsigned short)(w5 >> 16));
        a0 += b2f((unsigned short)w6); a1 += b2f((unsigned short)(w6 >> 16));
        a0 += b2f((unsigned short)w7); a1 += b2f((unsigned short)(w7 >> 16));
    }
    for (; j < c; j++){
        size_t s = (size_t)csr[start + j];
        unsigned v = *(const unsigned*)(hs + s * 64 + hl * 2);
        a0 += b2f((unsigned short)v);
        a1 += b2f((unsigned short)(v >> 16));
    }
    float dv = dinv[node];
    float2 bb = ((const float2*)b)[hl];
    float r0 = fmaf(dv, a0, bb.x);
    float r1 = fmaf(dv, a1, bb.y);
    *(unsigned*)(z + i * 64 + hl * 2) = (unsigned)f2b(r0) | ((unsigned)f2b(r1) << 16);
}

// ------- decode: out[e] = dot(z2[s], z2[t]); 4 edges/wave, uint2 loads ---------
// Grid: one 256-thread block covers 4 waves x 4 = 16 edges.
__global__ __launch_bounds__(256) void k_decode(const unsigned short* __restrict__ z,
                                                const int* __restrict__ es,
                                                const int* __restrict__ et,
                                                float* __restrict__ out, int m){
    int wv = (blockIdx.x * 256 + threadIdx.x) >> 6;
    int lane = threadIdx.x & 63;
    int e = wv * 4 + (lane >> 4);
    int ql = lane & 15;
    float p = 0.f;
    if (e < m){
        size_t s = (size_t)es[e], t2 = (size_t)et[e];
        uint2 vs = *(const uint2*)(z + s * 64 + ql * 4);
        uint2 vt = *(const uint2*)(z + t2 * 64 + ql * 4);
        p = b2f((unsigned short)vs.x) * b2f((unsigned short)vt.x)
          + b2f((unsigned short)(vs.x >> 16)) * b2f((unsigned short)(vt.x >> 16))
          + b2f((unsigned short)vs.y) * b2f((unsigned short)vt.y)
          + b2f((unsigned short)(vs.y >> 16)) * b2f((unsigned short)(vt.y >> 16));
    }
    #pragma unroll
    for (int o = 8; o > 0; o >>= 1) p += __shfl_xor(p, o);
    if (ql == 0 && e < m) out[e] = p;
}

// ---------------- launcher ----------------

extern "C" void kernel_launch(void* const* d_in, const int* in_sizes, int n_in,
                              void* d_out, int out_size, void* d_ws, size_t ws_size,
                              hipStream_t stream){
    const float* x   = (const float*)d_in[0];
    const int*   ei  = (const int*)d_in[1];
    const int*   eli = (const int*)d_in[2];
    const float* W1  = (const float*)d_in[3];
    const float* b1  = (const float*)d_in[4];
    const float* W2  = (const float*)d_in[5];
    const float* b2  = (const float*)d_in[6];
    float* out = (float*)d_out;

    int N_  = in_sizes[0] / 128;
    int E_  = in_sizes[1] / 2;
    int EL_ = in_sizes[2] / 2;
    int NBINS = (N_ + 127) >> 7;           // 782 for N=100k (must be <= 1024)
    const int EPB = 8192;
    int NBLK = (E_ + EPB - 1) / EPB;       // 196 for E=1.6M

    char* w = (char*)d_ws;
    size_t o = 0;
    auto alloc = [&](size_t bytes) -> size_t {
        size_t r = o; o += (bytes + 511) & ~(size_t)511; return r;
    };
    size_t o_cnt  = alloc((size_t)N_ * 4);
    size_t o_off  = alloc((size_t)N_ * 4);
    size_t o_dinv = alloc((size_t)N_ * 4);
    size_t o_gcur = alloc((size_t)NBINS * 4);
    size_t o_boff = alloc((size_t)(NBINS + 1) * 4);
    size_t o_csr  = alloc((size_t)E_ * 4);
    size_t o_wf1  = alloc(16384 * 2);
    size_t o_w2p  = alloc(4096 * 4);
    size_t o_hs1  = alloc((size_t)N_ * 128 * 2);   // 25.6MB; also hosts slab & z2
    size_t o_hs2  = alloc((size_t)N_ * 64 * 2);

    int* cnt  = (int*)(w + o_cnt);
    int* off  = (int*)(w + o_off);
    float* dinv = (float*)(w + o_dinv);
    int* gcur = (int*)(w + o_gcur);
    int* boff = (int*)(w + o_boff);
    int* csr  = (int*)(w + o_csr);
    unsigned short* wf1 = (unsigned short*)(w + o_wf1);
    unsigned* w2p = (unsigned*)(w + o_w2p);
    unsigned short* hs1 = (unsigned short*)(w + o_hs1);
    unsigned short* hs2 = (unsigned short*)(w + o_hs2);
    unsigned short* z2  = (unsigned short*)(w + o_hs1);  // hs1 dead after agg1g2

    // slab aliases the hs1 region (dead until k_gemm1 writes hs1):
    // NBINS*4096*4B = 12.8MB <= 25.6MB
    unsigned* slab = (unsigned*)(w + o_hs1);

    const int AGG1_BLOCKS = 2048;          // 8 blocks/CU (18.5KB LDS) -> 32 waves/CU
    int nwaves = AGG1_BLOCKS * 4;

    (void)hipMemsetAsync(gcur, 0, (size_t)NBINS * 4, stream);
    k_scatter2<<<NBLK, 256, 0, stream>>>(ei, ei + E_, gcur, slab, E_, NBINS);
    k_binscanB<<<1, 1024, 0, stream>>>(gcur, boff, NBINS);
    k_binsort <<<NBINS, 256, 0, stream>>>(slab, boff, csr, cnt, off, dinv, N_, NBINS);
    k_wconv   <<<24, 256, 0, stream>>>(W1, W2, wf1, w2p);
    k_gemm1   <<<(N_ + 63) / 64, 256, 0, stream>>>(x, wf1, dinv, hs1, N_);
    k_agg1g2  <<<AGG1_BLOCKS, 256, 0, stream>>>(hs1, off, cnt, csr, dinv, b1, w2p, hs2, N_, nwaves);
    k_agg2    <<<(N_ + 7) / 8, 256, 0, stream>>>(hs2, off, cnt, csr, dinv, b2, z2, N_);
    k_decode  <<<(EL_ + 15) / 16, 256, 0, stream>>>(z2, eli, eli + EL_, out, EL_);
}